// Round 14
// baseline (324.869 us; speedup 1.0000x reference)
//
#include <hip/hip_runtime.h>
#include <hip/hip_bf16.h>

// ---------------------------------------------------------------------------
// GCN 2-layer + edge dot logits, CSR-pull aggregation.
// agg[d] = dinv[d] * ( sum_{s in in(d)} hs[s] + hs[d] ) + b,  hs = (A@W)*dinv[row]
// Round 14: XCD-chunked pulls. Gather tables stored chunk-transposed
// [chunk][N][16]; chunk = blockIdx%8 pins each 3.2MB slice to one XCD's L2
// (blocks round-robin across XCDs) -> gathers become L2 hits instead of the
// ~3.6 TB/s L3-fill stream. Pull outputs stay linear (GEMM2/logits unchanged).
// CSR build: atomic-free fill via rank[] (r13). BM=32 conflict-free GEMM.
// ---------------------------------------------------------------------------

// count + per-edge rank within its dst segment (atomic returns old count)
__global__ void cnt_rank_k(const int* __restrict__ dst, int* __restrict__ cnt,
                           int* __restrict__ rank, int E) {
    int t = blockIdx.x * blockDim.x + threadIdx.x;
    int e = t * 4;
    if (e + 4 <= E) {
        int4 d4 = *reinterpret_cast<const int4*>(dst + e);
        int4 r4;
        r4.x = atomicAdd(&cnt[d4.x], 1);
        r4.y = atomicAdd(&cnt[d4.y], 1);
        r4.z = atomicAdd(&cnt[d4.z], 1);
        r4.w = atomicAdd(&cnt[d4.w], 1);
        *reinterpret_cast<int4*>(rank + e) = r4;   // coalesced
    } else {
        for (int i = e; i < E; i++) rank[i] = atomicAdd(&cnt[dst[i]], 1);
    }
}

__global__ void scan1_k(const int* __restrict__ cnt, int* __restrict__ incl,
                        int* __restrict__ bsum, int N) {
    __shared__ int sh[256];
    int i = blockIdx.x * 256 + threadIdx.x;
    int v = (i < N) ? cnt[i] : 0;
    sh[threadIdx.x] = v;
    __syncthreads();
#pragma unroll
    for (int off = 1; off < 256; off <<= 1) {
        int t = (threadIdx.x >= off) ? sh[threadIdx.x - off] : 0;
        __syncthreads();
        sh[threadIdx.x] += t;
        __syncthreads();
    }
    if (i < N) incl[i] = sh[threadIdx.x];
    if (threadIdx.x == 255) bsum[blockIdx.x] = sh[255];
}

// fused scan2+scan3: every block rescans bsum in LDS, then writeback (+dinv).
__global__ __launch_bounds__(256) void scan23_k(const int* __restrict__ cnt,
                                                const int* __restrict__ incl,
                                                const int* __restrict__ bsum,
                                                int* __restrict__ rowptr,
                                                float* __restrict__ dinv,
                                                int N, int E, int NB) {
    __shared__ int sh[256];
    __shared__ int blockOff;
    int v = (threadIdx.x < NB) ? bsum[threadIdx.x] : 0;
    sh[threadIdx.x] = v;
    __syncthreads();
#pragma unroll
    for (int off = 1; off < 256; off <<= 1) {
        int t = (threadIdx.x >= off) ? sh[threadIdx.x - off] : 0;
        __syncthreads();
        sh[threadIdx.x] += t;
        __syncthreads();
    }
    if (threadIdx.x == blockIdx.x) blockOff = sh[threadIdx.x] - v;  // exclusive
    __syncthreads();
    int i = blockIdx.x * 256 + threadIdx.x;
    if (i < N) {
        int c = cnt[i];
        rowptr[i] = incl[i] - c + blockOff;
        dinv[i] = rsqrtf(1.0f + (float)c);  // +1 self-loop
    }
    if (i == 0) rowptr[N] = E;
}

// ---------------------------------------------------------------------------
// GEMM body, BM=32, BK=16, 256 threads (conflict-free LDS maps).
// Output written CHUNK-TRANSPOSED: OutT[chunk][N][16] (chunk = 16 columns).
// ---------------------------------------------------------------------------
template <int BN, bool RELU>
__device__ __forceinline__ void gemm_body32(const float* __restrict__ A,
                                            const float* __restrict__ W,
                                            const float* __restrict__ dscale,
                                            float4* __restrict__ OutT,
                                            int M, int Nn, int row0,
                                            float (*As)[36], float (*Bs)[BN]) {
    constexpr int K = 128, BK = 16;
    constexpr int TN = BN / 16;  // 8 (BN=128) or 4 (BN=64)
    const int tid = threadIdx.x;
    const int tx = tid & 15, ty = tid >> 4;

    float acc[2][TN];
#pragma unroll
    for (int m = 0; m < 2; m++)
#pragma unroll
        for (int n = 0; n < TN; n++) acc[m][n] = 0.0f;

    for (int kt = 0; kt < K; kt += BK) {
        if (tid < 128) {
            int r = tid >> 2;
            int kq = (tid & 3) * 4;
            float4 av = make_float4(0.f, 0.f, 0.f, 0.f);
            int gr = row0 + r;
            if (gr < M)
                av = *reinterpret_cast<const float4*>(A + (size_t)gr * K + kt + kq);
            if (RELU) {
                av.x = fmaxf(av.x, 0.f); av.y = fmaxf(av.y, 0.f);
                av.z = fmaxf(av.z, 0.f); av.w = fmaxf(av.w, 0.f);
            }
            As[kq + 0][r] = av.x; As[kq + 1][r] = av.y;
            As[kq + 2][r] = av.z; As[kq + 3][r] = av.w;
        }
#pragma unroll
        for (int s = 0; s < (BK * BN) / (256 * 4); s++) {
            int f = s * 256 + tid;
            int brow = f / (BN / 4);
            int bcol = (f % (BN / 4)) * 4;
            float4 bv = *reinterpret_cast<const float4*>(W + (size_t)(kt + brow) * BN + bcol);
            *reinterpret_cast<float4*>(&Bs[brow][bcol]) = bv;
        }
        __syncthreads();

#pragma unroll
        for (int k = 0; k < BK; k++) {
            float2 a2 = *reinterpret_cast<const float2*>(&As[k][ty * 2]);
            float a[2] = {a2.x, a2.y};
            float b[TN];
            float4 b0 = *reinterpret_cast<const float4*>(&Bs[k][tx * 4]);
            b[0] = b0.x; b[1] = b0.y; b[2] = b0.z; b[3] = b0.w;
            if (TN == 8) {
                float4 b1 = *reinterpret_cast<const float4*>(&Bs[k][64 + tx * 4]);
                b[4] = b1.x; b[5] = b1.y; b[6] = b1.z; b[7] = b1.w;
            }
#pragma unroll
            for (int m = 0; m < 2; m++)
#pragma unroll
                for (int n = 0; n < TN; n++) acc[m][n] = fmaf(a[m], b[n], acc[m][n]);
        }
        __syncthreads();
    }

    const int chunk0 = tx >> 2;        // columns tx*4 -> chunk tx/4
    const int off = tx & 3;            // float4 slot within the 16-col chunk
#pragma unroll
    for (int m = 0; m < 2; m++) {
        int gr = row0 + ty * 2 + m;
        if (gr < M) {
            float dv = dscale[gr];
            float4 o0 = make_float4(acc[m][0] * dv, acc[m][1] * dv,
                                    acc[m][2] * dv, acc[m][3] * dv);
            OutT[((size_t)chunk0 * Nn + gr) * 4 + off] = o0;
            if (TN == 8) {
                float4 o1 = make_float4(acc[m][4] * dv, acc[m][5] * dv,
                                        acc[m][6] * dv, acc[m][7] * dv);
                OutT[((size_t)(4 + chunk0) * Nn + gr) * 4 + off] = o1;
            }
        }
    }
}

// ---------------------------------------------------------------------------
// FUSED (range-split): blocks [0,gemmBlocks) = GEMM1 -> hsT chunked; rest =
// atomic-free CSR fill: pos = rowptr[dst] + rank.
// ---------------------------------------------------------------------------
__global__ __launch_bounds__(256) void gemm1_fill_k(const float* __restrict__ A,
                                                    const float* __restrict__ W,
                                                    const float* __restrict__ dscale,
                                                    float4* __restrict__ OutT,
                                                    int M, int Nn,
                                                    const int* __restrict__ src,
                                                    const int* __restrict__ dst,
                                                    const int* __restrict__ rowptr,
                                                    const int* __restrict__ rank,
                                                    int* __restrict__ col,
                                                    int* __restrict__ eid, int E,
                                                    int gemmBlocks) {
    __shared__ float As[16][36];
    __shared__ float Bs[16][128];
    int g = (int)blockIdx.x;
    if (g >= gemmBlocks) {
        int t = (g - gemmBlocks) * 256 + threadIdx.x;
        int e = t * 4;
        if (e + 4 <= E) {
            int4 s4 = *reinterpret_cast<const int4*>(src + e);
            int4 d4 = *reinterpret_cast<const int4*>(dst + e);
            int4 r4 = *reinterpret_cast<const int4*>(rank + e);
            int p0 = rowptr[d4.x] + r4.x; col[p0] = s4.x; eid[p0] = e + 0;
            int p1 = rowptr[d4.y] + r4.y; col[p1] = s4.y; eid[p1] = e + 1;
            int p2 = rowptr[d4.z] + r4.z; col[p2] = s4.z; eid[p2] = e + 2;
            int p3 = rowptr[d4.w] + r4.w; col[p3] = s4.w; eid[p3] = e + 3;
        } else {
            for (int i = e; i < E; i++) {
                int pos = rowptr[dst[i]] + rank[i];
                col[pos] = src[i]; eid[pos] = i;
            }
        }
        return;
    }
    gemm_body32<128, false>(A, W, dscale, OutT, M, Nn, g * 32, As, Bs);
}

__global__ __launch_bounds__(256) void gemm2_k(const float* __restrict__ A,
                                               const float* __restrict__ W,
                                               const float* __restrict__ dscale,
                                               float4* __restrict__ OutT,
                                               int M, int Nn) {
    __shared__ float As[16][36];
    __shared__ float Bs[16][64];
    gemm_body32<64, true>(A, W, dscale, OutT, M, Nn, (int)blockIdx.x * 32, As, Bs);
}

// ---------------------------------------------------------------------------
// pull128 chunked: blockIdx = k*8 + c; chunk c (16 dims, 3.2MB slice) pinned
// to XCD c. Wave = one (node, chunk): 16 slots x 4 lanes; slot gathers one
// neighbor's 64B slice; cross-slot shfl reduce. Output agg1 LINEAR [N][128].
// ---------------------------------------------------------------------------
__global__ __launch_bounds__(256) void pull128c_k(const int* __restrict__ rowptr,
                                                  const int* __restrict__ col,
                                                  const float4* __restrict__ hsT,
                                                  const float* __restrict__ dinv,
                                                  const float4* __restrict__ bias4,
                                                  float4* __restrict__ out4, int N) {
    int c = (int)(blockIdx.x & 7);
    int k = (int)(blockIdx.x >> 3);
    int v = k * 4 + (int)(threadIdx.x >> 6);
    if (v >= N) return;
    int lane = threadIdx.x & 63;
    int s = lane >> 2, j = lane & 3;
    int p0 = rowptr[v], p1 = rowptr[v + 1];
    size_t cbase = (size_t)c * N;

    float4 acc = make_float4(0.f, 0.f, 0.f, 0.f);
    for (int p = p0 + s; p < p1; p += 16) {
        int u = col[p];
        float4 a = hsT[(cbase + u) * 4 + j];
        acc.x += a.x; acc.y += a.y; acc.z += a.z; acc.w += a.w;
    }
#pragma unroll
    for (int off = 4; off < 64; off <<= 1) {
        acc.x += __shfl_xor(acc.x, off);
        acc.y += __shfl_xor(acc.y, off);
        acc.z += __shfl_xor(acc.z, off);
        acc.w += __shfl_xor(acc.w, off);
    }
    if (s == 0) {
        float4 self = hsT[(cbase + v) * 4 + j];
        float dv = dinv[v];
        float4 bv = bias4[c * 4 + j];
        float4 o = make_float4(fmaf(acc.x + self.x, dv, bv.x),
                               fmaf(acc.y + self.y, dv, bv.y),
                               fmaf(acc.z + self.z, dv, bv.z),
                               fmaf(acc.w + self.w, dv, bv.w));
        out4[(size_t)v * 32 + c * 4 + j] = o;
    }
}

// ---------------------------------------------------------------------------
// pull64 chunked: blockIdx = k*8 + m; chunk = m&3 (16 dims, 3.2MB slice,
// resident on XCDs c and c+4), node base = k*8 + (m>>2)*4. Output LINEAR [N][64].
// ---------------------------------------------------------------------------
__global__ __launch_bounds__(256) void pull64c_k(const int* __restrict__ rowptr,
                                                 const int* __restrict__ col,
                                                 const float4* __restrict__ g2T,
                                                 const float* __restrict__ dinv,
                                                 const float4* __restrict__ bias4,
                                                 float4* __restrict__ out4, int N) {
    int m = (int)(blockIdx.x & 7);
    int c = m & 3;
    int k = (int)(blockIdx.x >> 3);
    int v = k * 8 + (m >> 2) * 4 + (int)(threadIdx.x >> 6);
    if (v >= N) return;
    int lane = threadIdx.x & 63;
    int s = lane >> 2, j = lane & 3;
    int p0 = rowptr[v], p1 = rowptr[v + 1];
    size_t cbase = (size_t)c * N;

    float4 acc = make_float4(0.f, 0.f, 0.f, 0.f);
    for (int p = p0 + s; p < p1; p += 16) {
        int u = col[p];
        float4 a = g2T[(cbase + u) * 4 + j];
        acc.x += a.x; acc.y += a.y; acc.z += a.z; acc.w += a.w;
    }
#pragma unroll
    for (int off = 4; off < 64; off <<= 1) {
        acc.x += __shfl_xor(acc.x, off);
        acc.y += __shfl_xor(acc.y, off);
        acc.z += __shfl_xor(acc.z, off);
        acc.w += __shfl_xor(acc.w, off);
    }
    if (s == 0) {
        float4 self = g2T[(cbase + v) * 4 + j];
        float dv = dinv[v];
        float4 bv = bias4[c * 4 + j];
        float4 o = make_float4(fmaf(acc.x + self.x, dv, bv.x),
                               fmaf(acc.y + self.y, dv, bv.y),
                               fmaf(acc.z + self.z, dv, bv.z),
                               fmaf(acc.w + self.w, dv, bv.w));
        out4[(size_t)v * 16 + c * 4 + j] = o;
    }
}

// ---------------------------------------------------------------------------
// logits (r13 structure, separate col/eid): one wave/dst; dst row resident.
// agg2 is LINEAR [N][64].
// ---------------------------------------------------------------------------
__global__ __launch_bounds__(256) void logits_csr_k(const int* __restrict__ rowptr,
                                                    const int* __restrict__ col,
                                                    const int* __restrict__ eid,
                                                    const float4* __restrict__ h4,
                                                    float* __restrict__ out, int N) {
    int v = (int)((blockIdx.x * (size_t)blockDim.x + threadIdx.x) >> 6);
    if (v >= N) return;
    int lane = threadIdx.x & 63;
    int q = lane & 15, slot = lane >> 4;
    int p0 = rowptr[v], p1 = rowptr[v + 1];
    if (p0 == p1) return;

    float4 rd = h4[(size_t)v * 16 + q];

    int p = p0;
    for (; p + 8 <= p1; p += 8) {
        int s0 = col[p + slot], s1 = col[p + 4 + slot];
        int e0 = eid[p + slot], e1 = eid[p + 4 + slot];
        float4 ra = h4[(size_t)s0 * 16 + q];
        float4 rb = h4[(size_t)s1 * 16 + q];
        float t0 = rd.x * ra.x + rd.y * ra.y + rd.z * ra.z + rd.w * ra.w;
        float t1 = rd.x * rb.x + rd.y * rb.y + rd.z * rb.z + rd.w * rb.w;
#pragma unroll
        for (int off = 1; off < 16; off <<= 1) {
            t0 += __shfl_xor(t0, off);
            t1 += __shfl_xor(t1, off);
        }
        if (q == 0) { out[e0] = t0; out[e1] = t1; }
    }
    for (; p + 4 <= p1; p += 4) {
        int s0 = col[p + slot];
        int e0 = eid[p + slot];
        float4 ra = h4[(size_t)s0 * 16 + q];
        float t0 = rd.x * ra.x + rd.y * ra.y + rd.z * ra.z + rd.w * ra.w;
#pragma unroll
        for (int off = 1; off < 16; off <<= 1) t0 += __shfl_xor(t0, off);
        if (q == 0) out[e0] = t0;
    }
    int rem = p1 - p;
    if (slot < rem) {
        int s0 = col[p + slot];
        int e0 = eid[p + slot];
        float4 ra = h4[(size_t)s0 * 16 + q];
        float t0 = rd.x * ra.x + rd.y * ra.y + rd.z * ra.z + rd.w * ra.w;
#pragma unroll
        for (int off = 1; off < 16; off <<= 1) t0 += __shfl_xor(t0, off);
        if (q == 0) out[e0] = t0;
    }
}

extern "C" void kernel_launch(void* const* d_in, const int* in_sizes, int n_in,
                              void* d_out, int out_size, void* d_ws, size_t ws_size,
                              hipStream_t stream) {
    const float* x  = (const float*)d_in[0];
    const int* ei   = (const int*)d_in[1];   // int32 (harness converts ints)
    const float* W1 = (const float*)d_in[2];
    const float* b1 = (const float*)d_in[3];
    const float* W2 = (const float*)d_in[4];
    const float* b2 = (const float*)d_in[5];
    float* out = (float*)d_out;

    const int N = in_sizes[0] / 128;   // 50000
    const int E = in_sizes[1] / 2;     // 800000
    const int* src = ei;
    const int* dst = ei + E;

    // ---- workspace ----
    // floats: dinv[50176] | bufA[N*128] | bufB[N*128]
    //   hsT = bufA (chunked [8][N][16]); agg1 = bufB (linear);
    //   g2T = bufA[0,N*64) (chunked [4][N][16]); agg2 = bufA[N*64,N*128) (linear)
    // ints: cnt[N] | incl[N] | rowptr[N+1] | bsum[256] | rank[E] | col[E] | eid[E]
    float* ws   = (float*)d_ws;
    float* dinv = ws;
    float* bufA = ws + 50176;
    float* bufB = bufA + (size_t)N * 128;
    float* hsT  = bufA;
    float* agg1 = bufB;
    float* g2T  = bufA;
    float* agg2 = bufA + (size_t)N * 64;

    int* ibase  = (int*)(bufB + (size_t)N * 128);
    int* cnt    = ibase;
    int* incl   = cnt + N;
    int* rowptr = incl + N;
    int* bsum   = rowptr + (N + 1);
    int* rank   = bsum + 256;
    int* col    = rank + E;
    int* eid    = col + E;

    const int B = 256;
    const int NB = (N + 255) / 256;   // 196
    const unsigned nodeBlocks = (unsigned)(((size_t)N * 64 + 255) / 256);  // 12500

    // ---- CSR count (+rank) + scan ----
    hipMemsetAsync(cnt, 0, (size_t)N * sizeof(int), stream);
    cnt_rank_k<<<(E / 4 + B - 1) / B, B, 0, stream>>>(dst, cnt, rank, E);
    scan1_k<<<NB, 256, 0, stream>>>(cnt, incl, bsum, N);
    scan23_k<<<NB, 256, 0, stream>>>(cnt, incl, bsum, rowptr, dinv, N, E, NB);

    // ---- fused: GEMM1 (hsT chunked) + atomic-free CSR fill ----
    {
        int gemmBlocks = (N + 31) / 32;              // 1563
        int fillBlocks = (E / 4 + B - 1) / B;        // 782
        gemm1_fill_k<<<gemmBlocks + fillBlocks, 256, 0, stream>>>(
            x, W1, dinv, (float4*)hsT, N, N, src, dst, rowptr, rank, col, eid, E,
            gemmBlocks);
    }

    // ---- layer 1 pull (chunked: 8 chunks x ceil(N/4) node-groups) ----
    {
        unsigned grid = (unsigned)(((N + 3) / 4)) * 8;   // 100000
        pull128c_k<<<grid, 256, 0, stream>>>(rowptr, col, (const float4*)hsT, dinv,
                                             (const float4*)b1, (float4*)agg1, N);
    }

    // ---- layer 2 GEMM (g2T chunked) ----
    gemm2_k<<<(N + 31) / 32, 256, 0, stream>>>(agg1, W2, dinv, (float4*)g2T, N, N);

    // ---- layer 2 pull (chunked: 4 chunks x 2 halves x ceil(N/8) groups) ----
    {
        unsigned grid = (unsigned)(((N + 7) / 8)) * 8;   // 50000
        pull64c_k<<<grid, 256, 0, stream>>>(rowptr, col, (const float4*)g2T, dinv,
                                            (const float4*)b2, (float4*)agg2, N);
    }

    // ---- edge logits (agg2 linear) ----
    logits_csr_k<<<nodeBlocks, 256, 0, stream>>>(rowptr, col, eid, (const float4*)agg2, out, N);
}

// Round 15
// 232.009 us; speedup vs baseline: 1.4002x; 1.4002x over previous
//
#include <hip/hip_runtime.h>
#include <hip/hip_bf16.h>

// ---------------------------------------------------------------------------
// GCN 2-layer + edge dot logits, CSR-pull aggregation.
// agg[d] = dinv[d] * ( sum_{s in in(d)} hs[s] + hs[d] ) + b,  hs = (A@W)*dinv[row]
// Round 15: XCD-chunked pulls v2. Gather tables chunk-transposed [c][N][16];
// chunk = blockIdx&7 pins each 3.2MB slice to one XCD's L2 (r14 proved FETCH
// 186->37MB). NEW: lane-group design -- 4 lanes own one (node,chunk) slice,
// serial 4-unrolled gather loop, no shfl reduce, no slot masks (r14's 8x
// per-node overhead removed). CSR: atomic-free fill via rank[] (r13).
// ---------------------------------------------------------------------------

// count + per-edge rank within its dst segment (atomic returns old count)
__global__ void cnt_rank_k(const int* __restrict__ dst, int* __restrict__ cnt,
                           int* __restrict__ rank, int E) {
    int t = blockIdx.x * blockDim.x + threadIdx.x;
    int e = t * 4;
    if (e + 4 <= E) {
        int4 d4 = *reinterpret_cast<const int4*>(dst + e);
        int4 r4;
        r4.x = atomicAdd(&cnt[d4.x], 1);
        r4.y = atomicAdd(&cnt[d4.y], 1);
        r4.z = atomicAdd(&cnt[d4.z], 1);
        r4.w = atomicAdd(&cnt[d4.w], 1);
        *reinterpret_cast<int4*>(rank + e) = r4;   // coalesced
    } else {
        for (int i = e; i < E; i++) rank[i] = atomicAdd(&cnt[dst[i]], 1);
    }
}

__global__ void scan1_k(const int* __restrict__ cnt, int* __restrict__ incl,
                        int* __restrict__ bsum, int N) {
    __shared__ int sh[256];
    int i = blockIdx.x * 256 + threadIdx.x;
    int v = (i < N) ? cnt[i] : 0;
    sh[threadIdx.x] = v;
    __syncthreads();
#pragma unroll
    for (int off = 1; off < 256; off <<= 1) {
        int t = (threadIdx.x >= off) ? sh[threadIdx.x - off] : 0;
        __syncthreads();
        sh[threadIdx.x] += t;
        __syncthreads();
    }
    if (i < N) incl[i] = sh[threadIdx.x];
    if (threadIdx.x == 255) bsum[blockIdx.x] = sh[255];
}

// fused scan2+scan3: every block rescans bsum in LDS, then writeback (+dinv).
__global__ __launch_bounds__(256) void scan23_k(const int* __restrict__ cnt,
                                                const int* __restrict__ incl,
                                                const int* __restrict__ bsum,
                                                int* __restrict__ rowptr,
                                                float* __restrict__ dinv,
                                                int N, int E, int NB) {
    __shared__ int sh[256];
    __shared__ int blockOff;
    int v = (threadIdx.x < NB) ? bsum[threadIdx.x] : 0;
    sh[threadIdx.x] = v;
    __syncthreads();
#pragma unroll
    for (int off = 1; off < 256; off <<= 1) {
        int t = (threadIdx.x >= off) ? sh[threadIdx.x - off] : 0;
        __syncthreads();
        sh[threadIdx.x] += t;
        __syncthreads();
    }
    if (threadIdx.x == blockIdx.x) blockOff = sh[threadIdx.x] - v;  // exclusive
    __syncthreads();
    int i = blockIdx.x * 256 + threadIdx.x;
    if (i < N) {
        int c = cnt[i];
        rowptr[i] = incl[i] - c + blockOff;
        dinv[i] = rsqrtf(1.0f + (float)c);  // +1 self-loop
    }
    if (i == 0) rowptr[N] = E;
}

// ---------------------------------------------------------------------------
// GEMM body, BM=32, BK=16, 256 threads (conflict-free LDS maps).
// Output CHUNK-TRANSPOSED: OutT[chunk][N][16].
// ---------------------------------------------------------------------------
template <int BN, bool RELU>
__device__ __forceinline__ void gemm_body32(const float* __restrict__ A,
                                            const float* __restrict__ W,
                                            const float* __restrict__ dscale,
                                            float4* __restrict__ OutT,
                                            int M, int Nn, int row0,
                                            float (*As)[36], float (*Bs)[BN]) {
    constexpr int K = 128, BK = 16;
    constexpr int TN = BN / 16;  // 8 (BN=128) or 4 (BN=64)
    const int tid = threadIdx.x;
    const int tx = tid & 15, ty = tid >> 4;

    float acc[2][TN];
#pragma unroll
    for (int m = 0; m < 2; m++)
#pragma unroll
        for (int n = 0; n < TN; n++) acc[m][n] = 0.0f;

    for (int kt = 0; kt < K; kt += BK) {
        if (tid < 128) {
            int r = tid >> 2;
            int kq = (tid & 3) * 4;
            float4 av = make_float4(0.f, 0.f, 0.f, 0.f);
            int gr = row0 + r;
            if (gr < M)
                av = *reinterpret_cast<const float4*>(A + (size_t)gr * K + kt + kq);
            if (RELU) {
                av.x = fmaxf(av.x, 0.f); av.y = fmaxf(av.y, 0.f);
                av.z = fmaxf(av.z, 0.f); av.w = fmaxf(av.w, 0.f);
            }
            As[kq + 0][r] = av.x; As[kq + 1][r] = av.y;
            As[kq + 2][r] = av.z; As[kq + 3][r] = av.w;
        }
#pragma unroll
        for (int s = 0; s < (BK * BN) / (256 * 4); s++) {
            int f = s * 256 + tid;
            int brow = f / (BN / 4);
            int bcol = (f % (BN / 4)) * 4;
            float4 bv = *reinterpret_cast<const float4*>(W + (size_t)(kt + brow) * BN + bcol);
            *reinterpret_cast<float4*>(&Bs[brow][bcol]) = bv;
        }
        __syncthreads();

#pragma unroll
        for (int k = 0; k < BK; k++) {
            float2 a2 = *reinterpret_cast<const float2*>(&As[k][ty * 2]);
            float a[2] = {a2.x, a2.y};
            float b[TN];
            float4 b0 = *reinterpret_cast<const float4*>(&Bs[k][tx * 4]);
            b[0] = b0.x; b[1] = b0.y; b[2] = b0.z; b[3] = b0.w;
            if (TN == 8) {
                float4 b1 = *reinterpret_cast<const float4*>(&Bs[k][64 + tx * 4]);
                b[4] = b1.x; b[5] = b1.y; b[6] = b1.z; b[7] = b1.w;
            }
#pragma unroll
            for (int m = 0; m < 2; m++)
#pragma unroll
                for (int n = 0; n < TN; n++) acc[m][n] = fmaf(a[m], b[n], acc[m][n]);
        }
        __syncthreads();
    }

    const int chunk0 = tx >> 2;        // columns tx*4 -> chunk tx/4
    const int off = tx & 3;            // float4 slot within the 16-col chunk
#pragma unroll
    for (int m = 0; m < 2; m++) {
        int gr = row0 + ty * 2 + m;
        if (gr < M) {
            float dv = dscale[gr];
            float4 o0 = make_float4(acc[m][0] * dv, acc[m][1] * dv,
                                    acc[m][2] * dv, acc[m][3] * dv);
            OutT[((size_t)chunk0 * Nn + gr) * 4 + off] = o0;
            if (TN == 8) {
                float4 o1 = make_float4(acc[m][4] * dv, acc[m][5] * dv,
                                        acc[m][6] * dv, acc[m][7] * dv);
                OutT[((size_t)(4 + chunk0) * Nn + gr) * 4 + off] = o1;
            }
        }
    }
}

// ---------------------------------------------------------------------------
// FUSED (range-split): blocks [0,gemmBlocks) = GEMM1 -> hsT chunked; rest =
// atomic-free CSR fill: pos = rowptr[dst] + rank.
// ---------------------------------------------------------------------------
__global__ __launch_bounds__(256) void gemm1_fill_k(const float* __restrict__ A,
                                                    const float* __restrict__ W,
                                                    const float* __restrict__ dscale,
                                                    float4* __restrict__ OutT,
                                                    int M, int Nn,
                                                    const int* __restrict__ src,
                                                    const int* __restrict__ dst,
                                                    const int* __restrict__ rowptr,
                                                    const int* __restrict__ rank,
                                                    int* __restrict__ col,
                                                    int* __restrict__ eid, int E,
                                                    int gemmBlocks) {
    __shared__ float As[16][36];
    __shared__ float Bs[16][128];
    int g = (int)blockIdx.x;
    if (g >= gemmBlocks) {
        int t = (g - gemmBlocks) * 256 + threadIdx.x;
        int e = t * 4;
        if (e + 4 <= E) {
            int4 s4 = *reinterpret_cast<const int4*>(src + e);
            int4 d4 = *reinterpret_cast<const int4*>(dst + e);
            int4 r4 = *reinterpret_cast<const int4*>(rank + e);
            int p0 = rowptr[d4.x] + r4.x; col[p0] = s4.x; eid[p0] = e + 0;
            int p1 = rowptr[d4.y] + r4.y; col[p1] = s4.y; eid[p1] = e + 1;
            int p2 = rowptr[d4.z] + r4.z; col[p2] = s4.z; eid[p2] = e + 2;
            int p3 = rowptr[d4.w] + r4.w; col[p3] = s4.w; eid[p3] = e + 3;
        } else {
            for (int i = e; i < E; i++) {
                int pos = rowptr[dst[i]] + rank[i];
                col[pos] = src[i]; eid[pos] = i;
            }
        }
        return;
    }
    gemm_body32<128, false>(A, W, dscale, OutT, M, Nn, g * 32, As, Bs);
}

__global__ __launch_bounds__(256) void gemm2_k(const float* __restrict__ A,
                                               const float* __restrict__ W,
                                               const float* __restrict__ dscale,
                                               float4* __restrict__ OutT,
                                               int M, int Nn) {
    __shared__ float As[16][36];
    __shared__ float Bs[16][64];
    gemm_body32<64, true>(A, W, dscale, OutT, M, Nn, (int)blockIdx.x * 32, As, Bs);
}

// ---------------------------------------------------------------------------
// pull128 chunked v2: blockIdx = g*8 + c -> chunk c (XCD c), nodes
// [g*64, g*64+64). 4 lanes per node: lane j holds float4 j of the 16-float
// slice. Serial 4-unrolled gather loop, register accumulate, no reduce.
// Output agg1 LINEAR [N][128].
// ---------------------------------------------------------------------------
__global__ __launch_bounds__(256) void pull128c_k(const int* __restrict__ rowptr,
                                                  const int* __restrict__ col,
                                                  const float4* __restrict__ hsT,
                                                  const float* __restrict__ dinv,
                                                  const float4* __restrict__ bias4,
                                                  float4* __restrict__ out4, int N) {
    int c = (int)(blockIdx.x & 7);
    int g = (int)(blockIdx.x >> 3);
    int v = g * 64 + (int)(threadIdx.x >> 2);
    if (v >= N) return;
    int j = threadIdx.x & 3;
    int p0 = rowptr[v], p1 = rowptr[v + 1];
    size_t cb = (size_t)c * N;

    float4 acc = hsT[(cb + v) * 4 + j];  // self row slice
    int p = p0;
    for (; p + 4 <= p1; p += 4) {
        int u0 = col[p], u1 = col[p + 1], u2 = col[p + 2], u3 = col[p + 3];
        float4 a = hsT[(cb + u0) * 4 + j];
        float4 b = hsT[(cb + u1) * 4 + j];
        float4 cc = hsT[(cb + u2) * 4 + j];
        float4 d = hsT[(cb + u3) * 4 + j];
        acc.x += (a.x + b.x) + (cc.x + d.x);
        acc.y += (a.y + b.y) + (cc.y + d.y);
        acc.z += (a.z + b.z) + (cc.z + d.z);
        acc.w += (a.w + b.w) + (cc.w + d.w);
    }
    for (; p < p1; p++) {
        float4 a = hsT[(cb + col[p]) * 4 + j];
        acc.x += a.x; acc.y += a.y; acc.z += a.z; acc.w += a.w;
    }

    float dv = dinv[v];
    float4 bv = bias4[c * 4 + j];
    out4[(size_t)v * 32 + c * 4 + j] =
        make_float4(fmaf(acc.x, dv, bv.x), fmaf(acc.y, dv, bv.y),
                    fmaf(acc.z, dv, bv.z), fmaf(acc.w, dv, bv.w));
}

// ---------------------------------------------------------------------------
// pull64 chunked v2: blockIdx = g*4 + c -> chunk c (slice lives on XCDs c,c+4),
// nodes [g*64, ...). Same lane-group design. Output agg2 LINEAR [N][64].
// ---------------------------------------------------------------------------
__global__ __launch_bounds__(256) void pull64c_k(const int* __restrict__ rowptr,
                                                 const int* __restrict__ col,
                                                 const float4* __restrict__ g2T,
                                                 const float* __restrict__ dinv,
                                                 const float4* __restrict__ bias4,
                                                 float4* __restrict__ out4, int N) {
    int c = (int)(blockIdx.x & 3);
    int g = (int)(blockIdx.x >> 2);
    int v = g * 64 + (int)(threadIdx.x >> 2);
    if (v >= N) return;
    int j = threadIdx.x & 3;
    int p0 = rowptr[v], p1 = rowptr[v + 1];
    size_t cb = (size_t)c * N;

    float4 acc = g2T[(cb + v) * 4 + j];  // self row slice
    int p = p0;
    for (; p + 4 <= p1; p += 4) {
        int u0 = col[p], u1 = col[p + 1], u2 = col[p + 2], u3 = col[p + 3];
        float4 a = g2T[(cb + u0) * 4 + j];
        float4 b = g2T[(cb + u1) * 4 + j];
        float4 cc = g2T[(cb + u2) * 4 + j];
        float4 d = g2T[(cb + u3) * 4 + j];
        acc.x += (a.x + b.x) + (cc.x + d.x);
        acc.y += (a.y + b.y) + (cc.y + d.y);
        acc.z += (a.z + b.z) + (cc.z + d.z);
        acc.w += (a.w + b.w) + (cc.w + d.w);
    }
    for (; p < p1; p++) {
        float4 a = g2T[(cb + col[p]) * 4 + j];
        acc.x += a.x; acc.y += a.y; acc.z += a.z; acc.w += a.w;
    }

    float dv = dinv[v];
    float4 bv = bias4[c * 4 + j];
    out4[(size_t)v * 16 + c * 4 + j] =
        make_float4(fmaf(acc.x, dv, bv.x), fmaf(acc.y, dv, bv.y),
                    fmaf(acc.z, dv, bv.z), fmaf(acc.w, dv, bv.w));
}

// ---------------------------------------------------------------------------
// logits (r13): one wave/dst; dst row wave-resident; src rows gathered.
// agg2 LINEAR [N][64].
// ---------------------------------------------------------------------------
__global__ __launch_bounds__(256) void logits_csr_k(const int* __restrict__ rowptr,
                                                    const int* __restrict__ col,
                                                    const int* __restrict__ eid,
                                                    const float4* __restrict__ h4,
                                                    float* __restrict__ out, int N) {
    int v = (int)((blockIdx.x * (size_t)blockDim.x + threadIdx.x) >> 6);
    if (v >= N) return;
    int lane = threadIdx.x & 63;
    int q = lane & 15, slot = lane >> 4;
    int p0 = rowptr[v], p1 = rowptr[v + 1];
    if (p0 == p1) return;

    float4 rd = h4[(size_t)v * 16 + q];

    int p = p0;
    for (; p + 8 <= p1; p += 8) {
        int s0 = col[p + slot], s1 = col[p + 4 + slot];
        int e0 = eid[p + slot], e1 = eid[p + 4 + slot];
        float4 ra = h4[(size_t)s0 * 16 + q];
        float4 rb = h4[(size_t)s1 * 16 + q];
        float t0 = rd.x * ra.x + rd.y * ra.y + rd.z * ra.z + rd.w * ra.w;
        float t1 = rd.x * rb.x + rd.y * rb.y + rd.z * rb.z + rd.w * rb.w;
#pragma unroll
        for (int off = 1; off < 16; off <<= 1) {
            t0 += __shfl_xor(t0, off);
            t1 += __shfl_xor(t1, off);
        }
        if (q == 0) { out[e0] = t0; out[e1] = t1; }
    }
    for (; p + 4 <= p1; p += 4) {
        int s0 = col[p + slot];
        int e0 = eid[p + slot];
        float4 ra = h4[(size_t)s0 * 16 + q];
        float t0 = rd.x * ra.x + rd.y * ra.y + rd.z * ra.z + rd.w * ra.w;
#pragma unroll
        for (int off = 1; off < 16; off <<= 1) t0 += __shfl_xor(t0, off);
        if (q == 0) out[e0] = t0;
    }
    int rem = p1 - p;
    if (slot < rem) {
        int s0 = col[p + slot];
        int e0 = eid[p + slot];
        float4 ra = h4[(size_t)s0 * 16 + q];
        float t0 = rd.x * ra.x + rd.y * ra.y + rd.z * ra.z + rd.w * ra.w;
#pragma unroll
        for (int off = 1; off < 16; off <<= 1) t0 += __shfl_xor(t0, off);
        if (q == 0) out[e0] = t0;
    }
}

extern "C" void kernel_launch(void* const* d_in, const int* in_sizes, int n_in,
                              void* d_out, int out_size, void* d_ws, size_t ws_size,
                              hipStream_t stream) {
    const float* x  = (const float*)d_in[0];
    const int* ei   = (const int*)d_in[1];   // int32 (harness converts ints)
    const float* W1 = (const float*)d_in[2];
    const float* b1 = (const float*)d_in[3];
    const float* W2 = (const float*)d_in[4];
    const float* b2 = (const float*)d_in[5];
    float* out = (float*)d_out;

    const int N = in_sizes[0] / 128;   // 50000
    const int E = in_sizes[1] / 2;     // 800000
    const int* src = ei;
    const int* dst = ei + E;

    // ---- workspace ----
    // floats: dinv[50176] | bufA[N*128] | bufB[N*128]
    //   hsT = bufA (chunked [8][N][16]); agg1 = bufB (linear);
    //   g2T = bufA[0,N*64) (chunked [4][N][16]); agg2 = bufA[N*64,N*128) (linear)
    // ints: cnt[N] | incl[N] | rowptr[N+1] | bsum[256] | rank[E] | col[E] | eid[E]
    float* ws   = (float*)d_ws;
    float* dinv = ws;
    float* bufA = ws + 50176;
    float* bufB = bufA + (size_t)N * 128;
    float* hsT  = bufA;
    float* agg1 = bufB;
    float* g2T  = bufA;
    float* agg2 = bufA + (size_t)N * 64;

    int* ibase  = (int*)(bufB + (size_t)N * 128);
    int* cnt    = ibase;
    int* incl   = cnt + N;
    int* rowptr = incl + N;
    int* bsum   = rowptr + (N + 1);
    int* rank   = bsum + 256;
    int* col    = rank + E;
    int* eid    = col + E;

    const int B = 256;
    const int NB = (N + 255) / 256;   // 196
    const unsigned nodeBlocks = (unsigned)(((size_t)N * 64 + 255) / 256);  // 12500
    const unsigned ng64 = (unsigned)((N + 63) / 64);                       // 782

    // ---- CSR count (+rank) + scan ----
    hipMemsetAsync(cnt, 0, (size_t)N * sizeof(int), stream);
    cnt_rank_k<<<(E / 4 + B - 1) / B, B, 0, stream>>>(dst, cnt, rank, E);
    scan1_k<<<NB, 256, 0, stream>>>(cnt, incl, bsum, N);
    scan23_k<<<NB, 256, 0, stream>>>(cnt, incl, bsum, rowptr, dinv, N, E, NB);

    // ---- fused: GEMM1 (hsT chunked) + atomic-free CSR fill ----
    {
        int gemmBlocks = (N + 31) / 32;              // 1563
        int fillBlocks = (E / 4 + B - 1) / B;        // 782
        gemm1_fill_k<<<gemmBlocks + fillBlocks, 256, 0, stream>>>(
            x, W1, dinv, (float4*)hsT, N, N, src, dst, rowptr, rank, col, eid, E,
            gemmBlocks);
    }

    // ---- layer 1 pull (8 chunks x 782 node-groups, lane-group design) ----
    pull128c_k<<<ng64 * 8, 256, 0, stream>>>(rowptr, col, (const float4*)hsT, dinv,
                                             (const float4*)b1, (float4*)agg1, N);

    // ---- layer 2 GEMM (g2T chunked) ----
    gemm2_k<<<(N + 31) / 32, 256, 0, stream>>>(agg1, W2, dinv, (float4*)g2T, N, N);

    // ---- layer 2 pull (4 chunks x 782 node-groups) ----
    pull64c_k<<<ng64 * 4, 256, 0, stream>>>(rowptr, col, (const float4*)g2T, dinv,
                                            (const float4*)b2, (float4*)agg2, N);

    // ---- edge logits (agg2 linear) ----
    logits_csr_k<<<nodeBlocks, 256, 0, stream>>>(rowptr, col, eid, (const float4*)agg2, out, N);
}

// Round 16
// 224.813 us; speedup vs baseline: 1.4451x; 1.0320x over previous
//
#include <hip/hip_runtime.h>
#include <hip/hip_bf16.h>

// ---------------------------------------------------------------------------
// GCN 2-layer + edge dot logits, CSR-pull aggregation.
// agg[d] = dinv[d] * ( sum_{s in in(d)} hs[s] + hs[d] ) + b,  hs = (A@W)*dinv[row]
// Round 16: all gather tables XCD-chunk-transposed [c][N][16] (slice pinned to
// an XCD L2; r14 proved FETCH 186->37MB). Lane-group pulls (r15). NEW:
// (a) agg2 stored chunked; logits = edge-order per-chunk partials (coalesced)
//     + reduce -> no eid array, no scattered out writes, no CSR in logits;
// (b) CSR fill stores only col (1 scattered 4B store/edge, was 2).
// CSR build: atomic-free fill via rank[] (r13).
// ---------------------------------------------------------------------------

// count + per-edge rank within its dst segment (atomic returns old count)
__global__ void cnt_rank_k(const int* __restrict__ dst, int* __restrict__ cnt,
                           int* __restrict__ rank, int E) {
    int t = blockIdx.x * blockDim.x + threadIdx.x;
    int e = t * 4;
    if (e + 4 <= E) {
        int4 d4 = *reinterpret_cast<const int4*>(dst + e);
        int4 r4;
        r4.x = atomicAdd(&cnt[d4.x], 1);
        r4.y = atomicAdd(&cnt[d4.y], 1);
        r4.z = atomicAdd(&cnt[d4.z], 1);
        r4.w = atomicAdd(&cnt[d4.w], 1);
        *reinterpret_cast<int4*>(rank + e) = r4;   // coalesced
    } else {
        for (int i = e; i < E; i++) rank[i] = atomicAdd(&cnt[dst[i]], 1);
    }
}

__global__ void scan1_k(const int* __restrict__ cnt, int* __restrict__ incl,
                        int* __restrict__ bsum, int N) {
    __shared__ int sh[256];
    int i = blockIdx.x * 256 + threadIdx.x;
    int v = (i < N) ? cnt[i] : 0;
    sh[threadIdx.x] = v;
    __syncthreads();
#pragma unroll
    for (int off = 1; off < 256; off <<= 1) {
        int t = (threadIdx.x >= off) ? sh[threadIdx.x - off] : 0;
        __syncthreads();
        sh[threadIdx.x] += t;
        __syncthreads();
    }
    if (i < N) incl[i] = sh[threadIdx.x];
    if (threadIdx.x == 255) bsum[blockIdx.x] = sh[255];
}

// fused scan2+scan3: every block rescans bsum in LDS, then writeback (+dinv).
__global__ __launch_bounds__(256) void scan23_k(const int* __restrict__ cnt,
                                                const int* __restrict__ incl,
                                                const int* __restrict__ bsum,
                                                int* __restrict__ rowptr,
                                                float* __restrict__ dinv,
                                                int N, int E, int NB) {
    __shared__ int sh[256];
    __shared__ int blockOff;
    int v = (threadIdx.x < NB) ? bsum[threadIdx.x] : 0;
    sh[threadIdx.x] = v;
    __syncthreads();
#pragma unroll
    for (int off = 1; off < 256; off <<= 1) {
        int t = (threadIdx.x >= off) ? sh[threadIdx.x - off] : 0;
        __syncthreads();
        sh[threadIdx.x] += t;
        __syncthreads();
    }
    if (threadIdx.x == blockIdx.x) blockOff = sh[threadIdx.x] - v;  // exclusive
    __syncthreads();
    int i = blockIdx.x * 256 + threadIdx.x;
    if (i < N) {
        int c = cnt[i];
        rowptr[i] = incl[i] - c + blockOff;
        dinv[i] = rsqrtf(1.0f + (float)c);  // +1 self-loop
    }
    if (i == 0) rowptr[N] = E;
}

// ---------------------------------------------------------------------------
// GEMM body, BM=32, BK=16, 256 threads (conflict-free LDS maps).
// Output CHUNK-TRANSPOSED: OutT[chunk][N][16].
// ---------------------------------------------------------------------------
template <int BN, bool RELU>
__device__ __forceinline__ void gemm_body32(const float* __restrict__ A,
                                            const float* __restrict__ W,
                                            const float* __restrict__ dscale,
                                            float4* __restrict__ OutT,
                                            int M, int Nn, int row0,
                                            float (*As)[36], float (*Bs)[BN]) {
    constexpr int K = 128, BK = 16;
    constexpr int TN = BN / 16;  // 8 (BN=128) or 4 (BN=64)
    const int tid = threadIdx.x;
    const int tx = tid & 15, ty = tid >> 4;

    float acc[2][TN];
#pragma unroll
    for (int m = 0; m < 2; m++)
#pragma unroll
        for (int n = 0; n < TN; n++) acc[m][n] = 0.0f;

    for (int kt = 0; kt < K; kt += BK) {
        if (tid < 128) {
            int r = tid >> 2;
            int kq = (tid & 3) * 4;
            float4 av = make_float4(0.f, 0.f, 0.f, 0.f);
            int gr = row0 + r;
            if (gr < M)
                av = *reinterpret_cast<const float4*>(A + (size_t)gr * K + kt + kq);
            if (RELU) {
                av.x = fmaxf(av.x, 0.f); av.y = fmaxf(av.y, 0.f);
                av.z = fmaxf(av.z, 0.f); av.w = fmaxf(av.w, 0.f);
            }
            As[kq + 0][r] = av.x; As[kq + 1][r] = av.y;
            As[kq + 2][r] = av.z; As[kq + 3][r] = av.w;
        }
#pragma unroll
        for (int s = 0; s < (BK * BN) / (256 * 4); s++) {
            int f = s * 256 + tid;
            int brow = f / (BN / 4);
            int bcol = (f % (BN / 4)) * 4;
            float4 bv = *reinterpret_cast<const float4*>(W + (size_t)(kt + brow) * BN + bcol);
            *reinterpret_cast<float4*>(&Bs[brow][bcol]) = bv;
        }
        __syncthreads();

#pragma unroll
        for (int k = 0; k < BK; k++) {
            float2 a2 = *reinterpret_cast<const float2*>(&As[k][ty * 2]);
            float a[2] = {a2.x, a2.y};
            float b[TN];
            float4 b0 = *reinterpret_cast<const float4*>(&Bs[k][tx * 4]);
            b[0] = b0.x; b[1] = b0.y; b[2] = b0.z; b[3] = b0.w;
            if (TN == 8) {
                float4 b1 = *reinterpret_cast<const float4*>(&Bs[k][64 + tx * 4]);
                b[4] = b1.x; b[5] = b1.y; b[6] = b1.z; b[7] = b1.w;
            }
#pragma unroll
            for (int m = 0; m < 2; m++)
#pragma unroll
                for (int n = 0; n < TN; n++) acc[m][n] = fmaf(a[m], b[n], acc[m][n]);
        }
        __syncthreads();
    }

    const int chunk0 = tx >> 2;        // columns tx*4 -> chunk tx/4
    const int off = tx & 3;            // float4 slot within the 16-col chunk
#pragma unroll
    for (int m = 0; m < 2; m++) {
        int gr = row0 + ty * 2 + m;
        if (gr < M) {
            float dv = dscale[gr];
            float4 o0 = make_float4(acc[m][0] * dv, acc[m][1] * dv,
                                    acc[m][2] * dv, acc[m][3] * dv);
            OutT[((size_t)chunk0 * Nn + gr) * 4 + off] = o0;
            if (TN == 8) {
                float4 o1 = make_float4(acc[m][4] * dv, acc[m][5] * dv,
                                        acc[m][6] * dv, acc[m][7] * dv);
                OutT[((size_t)(4 + chunk0) * Nn + gr) * 4 + off] = o1;
            }
        }
    }
}

// ---------------------------------------------------------------------------
// FUSED (range-split): blocks [0,gemmBlocks) = GEMM1 -> hsT chunked; rest =
// atomic-free CSR fill: col[rowptr[dst]+rank] = src  (ONE scattered store).
// ---------------------------------------------------------------------------
__global__ __launch_bounds__(256) void gemm1_fill_k(const float* __restrict__ A,
                                                    const float* __restrict__ W,
                                                    const float* __restrict__ dscale,
                                                    float4* __restrict__ OutT,
                                                    int M, int Nn,
                                                    const int* __restrict__ src,
                                                    const int* __restrict__ dst,
                                                    const int* __restrict__ rowptr,
                                                    const int* __restrict__ rank,
                                                    int* __restrict__ col, int E,
                                                    int gemmBlocks) {
    __shared__ float As[16][36];
    __shared__ float Bs[16][128];
    int g = (int)blockIdx.x;
    if (g >= gemmBlocks) {
        int t = (g - gemmBlocks) * 256 + threadIdx.x;
        int e = t * 4;
        if (e + 4 <= E) {
            int4 s4 = *reinterpret_cast<const int4*>(src + e);
            int4 d4 = *reinterpret_cast<const int4*>(dst + e);
            int4 r4 = *reinterpret_cast<const int4*>(rank + e);
            col[rowptr[d4.x] + r4.x] = s4.x;
            col[rowptr[d4.y] + r4.y] = s4.y;
            col[rowptr[d4.z] + r4.z] = s4.z;
            col[rowptr[d4.w] + r4.w] = s4.w;
        } else {
            for (int i = e; i < E; i++)
                col[rowptr[dst[i]] + rank[i]] = src[i];
        }
        return;
    }
    gemm_body32<128, false>(A, W, dscale, OutT, M, Nn, g * 32, As, Bs);
}

__global__ __launch_bounds__(256) void gemm2_k(const float* __restrict__ A,
                                               const float* __restrict__ W,
                                               const float* __restrict__ dscale,
                                               float4* __restrict__ OutT,
                                               int M, int Nn) {
    __shared__ float As[16][36];
    __shared__ float Bs[16][64];
    gemm_body32<64, true>(A, W, dscale, OutT, M, Nn, (int)blockIdx.x * 32, As, Bs);
}

// ---------------------------------------------------------------------------
// pull128 chunked (r15): blockIdx = g*8 + c -> chunk c (XCD c), nodes
// [g*64, g*64+64). 4 lanes per node; serial 4-unrolled gather; no reduce.
// Output agg1 LINEAR [N][128].
// ---------------------------------------------------------------------------
__global__ __launch_bounds__(256) void pull128c_k(const int* __restrict__ rowptr,
                                                  const int* __restrict__ col,
                                                  const float4* __restrict__ hsT,
                                                  const float* __restrict__ dinv,
                                                  const float4* __restrict__ bias4,
                                                  float4* __restrict__ out4, int N) {
    int c = (int)(blockIdx.x & 7);
    int g = (int)(blockIdx.x >> 3);
    int v = g * 64 + (int)(threadIdx.x >> 2);
    if (v >= N) return;
    int j = threadIdx.x & 3;
    int p0 = rowptr[v], p1 = rowptr[v + 1];
    size_t cb = (size_t)c * N;

    float4 acc = hsT[(cb + v) * 4 + j];  // self row slice
    int p = p0;
    for (; p + 4 <= p1; p += 4) {
        int u0 = col[p], u1 = col[p + 1], u2 = col[p + 2], u3 = col[p + 3];
        float4 a = hsT[(cb + u0) * 4 + j];
        float4 b = hsT[(cb + u1) * 4 + j];
        float4 cc = hsT[(cb + u2) * 4 + j];
        float4 d = hsT[(cb + u3) * 4 + j];
        acc.x += (a.x + b.x) + (cc.x + d.x);
        acc.y += (a.y + b.y) + (cc.y + d.y);
        acc.z += (a.z + b.z) + (cc.z + d.z);
        acc.w += (a.w + b.w) + (cc.w + d.w);
    }
    for (; p < p1; p++) {
        float4 a = hsT[(cb + col[p]) * 4 + j];
        acc.x += a.x; acc.y += a.y; acc.z += a.z; acc.w += a.w;
    }

    float dv = dinv[v];
    float4 bv = bias4[c * 4 + j];
    out4[(size_t)v * 32 + c * 4 + j] =
        make_float4(fmaf(acc.x, dv, bv.x), fmaf(acc.y, dv, bv.y),
                    fmaf(acc.z, dv, bv.z), fmaf(acc.w, dv, bv.w));
}

// ---------------------------------------------------------------------------
// pull64 chunked: blockIdx = g*4 + c (slice on XCDs c,c+4). Output agg2T
// CHUNKED [4][N][16] (consumed by edge-order chunked logits).
// ---------------------------------------------------------------------------
__global__ __launch_bounds__(256) void pull64c_k(const int* __restrict__ rowptr,
                                                 const int* __restrict__ col,
                                                 const float4* __restrict__ g2T,
                                                 const float* __restrict__ dinv,
                                                 const float4* __restrict__ bias4,
                                                 float4* __restrict__ outT, int N) {
    int c = (int)(blockIdx.x & 3);
    int g = (int)(blockIdx.x >> 2);
    int v = g * 64 + (int)(threadIdx.x >> 2);
    if (v >= N) return;
    int j = threadIdx.x & 3;
    int p0 = rowptr[v], p1 = rowptr[v + 1];
    size_t cb = (size_t)c * N;

    float4 acc = g2T[(cb + v) * 4 + j];  // self row slice
    int p = p0;
    for (; p + 4 <= p1; p += 4) {
        int u0 = col[p], u1 = col[p + 1], u2 = col[p + 2], u3 = col[p + 3];
        float4 a = g2T[(cb + u0) * 4 + j];
        float4 b = g2T[(cb + u1) * 4 + j];
        float4 cc = g2T[(cb + u2) * 4 + j];
        float4 d = g2T[(cb + u3) * 4 + j];
        acc.x += (a.x + b.x) + (cc.x + d.x);
        acc.y += (a.y + b.y) + (cc.y + d.y);
        acc.z += (a.z + b.z) + (cc.z + d.z);
        acc.w += (a.w + b.w) + (cc.w + d.w);
    }
    for (; p < p1; p++) {
        float4 a = g2T[(cb + col[p]) * 4 + j];
        acc.x += a.x; acc.y += a.y; acc.z += a.z; acc.w += a.w;
    }

    float dv = dinv[v];
    float4 bv = bias4[c * 4 + j];
    outT[(cb + v) * 4 + j] =
        make_float4(fmaf(acc.x, dv, bv.x), fmaf(acc.y, dv, bv.y),
                    fmaf(acc.z, dv, bv.z), fmaf(acc.w, dv, bv.w));
}

// ---------------------------------------------------------------------------
// logits part: edge-order, chunk c = blockIdx&3 (slice on XCDs c,c+4).
// 4-lane group per edge; both endpoint 64B slices gathered (L2-pinned hits);
// part[c*E + e] written coalesced (lane j==0, e consecutive across groups).
// ---------------------------------------------------------------------------
__global__ __launch_bounds__(256) void logits_part_k(const int* __restrict__ src,
                                                     const int* __restrict__ dst,
                                                     const float4* __restrict__ aggT,
                                                     float* __restrict__ part,
                                                     int N, int E) {
    int c = (int)(blockIdx.x & 3);
    int blk = (int)(blockIdx.x >> 2);
    int g = (int)(threadIdx.x >> 2);   // 64 groups
    int j = threadIdx.x & 3;
    size_t cb = (size_t)c * N;
    int ebase = blk * 256;

#pragma unroll
    for (int i = 0; i < 4; i++) {
        int e = ebase + i * 64 + g;    // consecutive across groups -> coalesced
        if (e < E) {
            int s = src[e], d = dst[e];
            float4 a = aggT[(cb + s) * 4 + j];
            float4 b = aggT[(cb + d) * 4 + j];
            float t = a.x * b.x + a.y * b.y + a.z * b.z + a.w * b.w;
            t += __shfl_xor(t, 1);
            t += __shfl_xor(t, 2);
            if (j == 0) part[(size_t)c * E + e] = t;
        }
    }
}

// out[e] = sum of 4 chunk partials; fully coalesced float4 I/O.
__global__ __launch_bounds__(256) void logits_reduce_k(const float* __restrict__ part,
                                                       float* __restrict__ out, int E) {
    int i = blockIdx.x * blockDim.x + threadIdx.x;   // float4 index
    int e4 = E >> 2;
    if (i < e4) {
        const float4* p0 = reinterpret_cast<const float4*>(part);
        const float4* p1 = reinterpret_cast<const float4*>(part + (size_t)E);
        const float4* p2 = reinterpret_cast<const float4*>(part + (size_t)E * 2);
        const float4* p3 = reinterpret_cast<const float4*>(part + (size_t)E * 3);
        float4 a = p0[i], b = p1[i], c = p2[i], d = p3[i];
        float4 o = make_float4((a.x + b.x) + (c.x + d.x), (a.y + b.y) + (c.y + d.y),
                               (a.z + b.z) + (c.z + d.z), (a.w + b.w) + (c.w + d.w));
        reinterpret_cast<float4*>(out)[i] = o;
    }
    // tail (E not multiple of 4)
    int tail = e4 * 4 + i;
    if (i < (E & 3) + 0 && false) {}
    if (blockIdx.x == 0 && threadIdx.x < (E & 3)) {
        int e = e4 * 4 + threadIdx.x;
        out[e] = part[e] + part[(size_t)E + e] + part[(size_t)E * 2 + e] +
                 part[(size_t)E * 3 + e];
    }
}

extern "C" void kernel_launch(void* const* d_in, const int* in_sizes, int n_in,
                              void* d_out, int out_size, void* d_ws, size_t ws_size,
                              hipStream_t stream) {
    const float* x  = (const float*)d_in[0];
    const int* ei   = (const int*)d_in[1];   // int32 (harness converts ints)
    const float* W1 = (const float*)d_in[2];
    const float* b1 = (const float*)d_in[3];
    const float* W2 = (const float*)d_in[4];
    const float* b2 = (const float*)d_in[5];
    float* out = (float*)d_out;

    const int N = in_sizes[0] / 128;   // 50000
    const int E = in_sizes[1] / 2;     // 800000
    const int* src = ei;
    const int* dst = ei + E;

    // ---- workspace ----
    // floats: dinv[50176] | bufA[N*128] | bufB[N*128]
    //   hsT   = bufA            (chunked [8][N][16])
    //   agg1  = bufB            (linear [N][128]; dead after gemm2)
    //   g2T   = bufA[0,  N*64)  (chunked [4][N][16])
    //   agg2T = bufA[N*64,N*128)(chunked [4][N][16])
    //   part  = bufB[0, 4E)     (overlays dead agg1)
    // ints: cnt[N] | incl[N] | rowptr[N+1] | bsum[256] | rank[E] | col[E]
    float* ws    = (float*)d_ws;
    float* dinv  = ws;
    float* bufA  = ws + 50176;
    float* bufB  = bufA + (size_t)N * 128;
    float* hsT   = bufA;
    float* agg1  = bufB;
    float* g2T   = bufA;
    float* agg2T = bufA + (size_t)N * 64;
    float* part  = bufB;

    int* ibase  = (int*)(bufB + (size_t)N * 128);
    int* cnt    = ibase;
    int* incl   = cnt + N;
    int* rowptr = incl + N;
    int* bsum   = rowptr + (N + 1);
    int* rank   = bsum + 256;
    int* col    = rank + E;

    const int B = 256;
    const int NB = (N + 255) / 256;              // 196
    const unsigned ng64 = (unsigned)((N + 63) / 64);  // 782

    // ---- CSR count (+rank) + scan ----
    hipMemsetAsync(cnt, 0, (size_t)N * sizeof(int), stream);
    cnt_rank_k<<<(E / 4 + B - 1) / B, B, 0, stream>>>(dst, cnt, rank, E);
    scan1_k<<<NB, 256, 0, stream>>>(cnt, incl, bsum, N);
    scan23_k<<<NB, 256, 0, stream>>>(cnt, incl, bsum, rowptr, dinv, N, E, NB);

    // ---- fused: GEMM1 (hsT chunked) + atomic-free CSR fill (col only) ----
    {
        int gemmBlocks = (N + 31) / 32;              // 1563
        int fillBlocks = (E / 4 + B - 1) / B;        // 782
        gemm1_fill_k<<<gemmBlocks + fillBlocks, 256, 0, stream>>>(
            x, W1, dinv, (float4*)hsT, N, N, src, dst, rowptr, rank, col, E,
            gemmBlocks);
    }

    // ---- layer 1 pull (8 chunks x 782 node-groups) -> agg1 linear ----
    pull128c_k<<<ng64 * 8, 256, 0, stream>>>(rowptr, col, (const float4*)hsT, dinv,
                                             (const float4*)b1, (float4*)agg1, N);

    // ---- layer 2 GEMM -> g2T chunked ----
    gemm2_k<<<(N + 31) / 32, 256, 0, stream>>>(agg1, W2, dinv, (float4*)g2T, N, N);

    // ---- layer 2 pull (4 chunks x 782 node-groups) -> agg2T chunked ----
    pull64c_k<<<ng64 * 4, 256, 0, stream>>>(rowptr, col, (const float4*)g2T, dinv,
                                            (const float4*)b2, (float4*)agg2T, N);

    // ---- logits: edge-order chunked partials + reduce ----
    {
        unsigned blk = (unsigned)((E + 255) / 256);   // 3125
        logits_part_k<<<blk * 4, 256, 0, stream>>>(src, dst, (const float4*)agg2T,
                                                   part, N, E);
        unsigned rblk = (unsigned)((E / 4 + 255) / 256);  // 782
        logits_reduce_k<<<rblk, 256, 0, stream>>>(part, out, E);
    }
}

// Round 17
// 215.712 us; speedup vs baseline: 1.5060x; 1.0422x over previous
//
#include <hip/hip_runtime.h>
#include <hip/hip_bf16.h>

// ---------------------------------------------------------------------------
// GCN 2-layer + edge dot logits, CSR-pull aggregation.
// agg[d] = dinv[d] * ( sum_{s in in(d)} hs[s] + hs[d] ) + b,  hs = (A@W)*dinv[row]
// Round 17: r16 structure (XCD-chunked tables [c][N][16], lane-group pulls,
// edge-order chunked logits, atomic-free fill). NEW: (a) col stored as ushort
// (node ids < 65536) -- halves the index stream that every chunk pass re-reads;
// (b) pulls use 8-deep unroll + next-block index prefetch (L2-hit latency
// regime: break the col->gather serial chain).
// ---------------------------------------------------------------------------

using ushort_t = unsigned short;

// count + per-edge rank within its dst segment (atomic returns old count)
__global__ void cnt_rank_k(const int* __restrict__ dst, int* __restrict__ cnt,
                           int* __restrict__ rank, int E) {
    int t = blockIdx.x * blockDim.x + threadIdx.x;
    int e = t * 4;
    if (e + 4 <= E) {
        int4 d4 = *reinterpret_cast<const int4*>(dst + e);
        int4 r4;
        r4.x = atomicAdd(&cnt[d4.x], 1);
        r4.y = atomicAdd(&cnt[d4.y], 1);
        r4.z = atomicAdd(&cnt[d4.z], 1);
        r4.w = atomicAdd(&cnt[d4.w], 1);
        *reinterpret_cast<int4*>(rank + e) = r4;   // coalesced
    } else {
        for (int i = e; i < E; i++) rank[i] = atomicAdd(&cnt[dst[i]], 1);
    }
}

__global__ void scan1_k(const int* __restrict__ cnt, int* __restrict__ incl,
                        int* __restrict__ bsum, int N) {
    __shared__ int sh[256];
    int i = blockIdx.x * 256 + threadIdx.x;
    int v = (i < N) ? cnt[i] : 0;
    sh[threadIdx.x] = v;
    __syncthreads();
#pragma unroll
    for (int off = 1; off < 256; off <<= 1) {
        int t = (threadIdx.x >= off) ? sh[threadIdx.x - off] : 0;
        __syncthreads();
        sh[threadIdx.x] += t;
        __syncthreads();
    }
    if (i < N) incl[i] = sh[threadIdx.x];
    if (threadIdx.x == 255) bsum[blockIdx.x] = sh[255];
}

// fused scan2+scan3: every block rescans bsum in LDS, then writeback (+dinv).
__global__ __launch_bounds__(256) void scan23_k(const int* __restrict__ cnt,
                                                const int* __restrict__ incl,
                                                const int* __restrict__ bsum,
                                                int* __restrict__ rowptr,
                                                float* __restrict__ dinv,
                                                int N, int E, int NB) {
    __shared__ int sh[256];
    __shared__ int blockOff;
    int v = (threadIdx.x < NB) ? bsum[threadIdx.x] : 0;
    sh[threadIdx.x] = v;
    __syncthreads();
#pragma unroll
    for (int off = 1; off < 256; off <<= 1) {
        int t = (threadIdx.x >= off) ? sh[threadIdx.x - off] : 0;
        __syncthreads();
        sh[threadIdx.x] += t;
        __syncthreads();
    }
    if (threadIdx.x == blockIdx.x) blockOff = sh[threadIdx.x] - v;  // exclusive
    __syncthreads();
    int i = blockIdx.x * 256 + threadIdx.x;
    if (i < N) {
        int c = cnt[i];
        rowptr[i] = incl[i] - c + blockOff;
        dinv[i] = rsqrtf(1.0f + (float)c);  // +1 self-loop
    }
    if (i == 0) rowptr[N] = E;
}

// ---------------------------------------------------------------------------
// GEMM body, BM=32, BK=16, 256 threads (conflict-free LDS maps).
// Output CHUNK-TRANSPOSED: OutT[chunk][N][16].
// ---------------------------------------------------------------------------
template <int BN, bool RELU>
__device__ __forceinline__ void gemm_body32(const float* __restrict__ A,
                                            const float* __restrict__ W,
                                            const float* __restrict__ dscale,
                                            float4* __restrict__ OutT,
                                            int M, int Nn, int row0,
                                            float (*As)[36], float (*Bs)[BN]) {
    constexpr int K = 128, BK = 16;
    constexpr int TN = BN / 16;  // 8 (BN=128) or 4 (BN=64)
    const int tid = threadIdx.x;
    const int tx = tid & 15, ty = tid >> 4;

    float acc[2][TN];
#pragma unroll
    for (int m = 0; m < 2; m++)
#pragma unroll
        for (int n = 0; n < TN; n++) acc[m][n] = 0.0f;

    for (int kt = 0; kt < K; kt += BK) {
        if (tid < 128) {
            int r = tid >> 2;
            int kq = (tid & 3) * 4;
            float4 av = make_float4(0.f, 0.f, 0.f, 0.f);
            int gr = row0 + r;
            if (gr < M)
                av = *reinterpret_cast<const float4*>(A + (size_t)gr * K + kt + kq);
            if (RELU) {
                av.x = fmaxf(av.x, 0.f); av.y = fmaxf(av.y, 0.f);
                av.z = fmaxf(av.z, 0.f); av.w = fmaxf(av.w, 0.f);
            }
            As[kq + 0][r] = av.x; As[kq + 1][r] = av.y;
            As[kq + 2][r] = av.z; As[kq + 3][r] = av.w;
        }
#pragma unroll
        for (int s = 0; s < (BK * BN) / (256 * 4); s++) {
            int f = s * 256 + tid;
            int brow = f / (BN / 4);
            int bcol = (f % (BN / 4)) * 4;
            float4 bv = *reinterpret_cast<const float4*>(W + (size_t)(kt + brow) * BN + bcol);
            *reinterpret_cast<float4*>(&Bs[brow][bcol]) = bv;
        }
        __syncthreads();

#pragma unroll
        for (int k = 0; k < BK; k++) {
            float2 a2 = *reinterpret_cast<const float2*>(&As[k][ty * 2]);
            float a[2] = {a2.x, a2.y};
            float b[TN];
            float4 b0 = *reinterpret_cast<const float4*>(&Bs[k][tx * 4]);
            b[0] = b0.x; b[1] = b0.y; b[2] = b0.z; b[3] = b0.w;
            if (TN == 8) {
                float4 b1 = *reinterpret_cast<const float4*>(&Bs[k][64 + tx * 4]);
                b[4] = b1.x; b[5] = b1.y; b[6] = b1.z; b[7] = b1.w;
            }
#pragma unroll
            for (int m = 0; m < 2; m++)
#pragma unroll
                for (int n = 0; n < TN; n++) acc[m][n] = fmaf(a[m], b[n], acc[m][n]);
        }
        __syncthreads();
    }

    const int chunk0 = tx >> 2;
    const int off = tx & 3;
#pragma unroll
    for (int m = 0; m < 2; m++) {
        int gr = row0 + ty * 2 + m;
        if (gr < M) {
            float dv = dscale[gr];
            float4 o0 = make_float4(acc[m][0] * dv, acc[m][1] * dv,
                                    acc[m][2] * dv, acc[m][3] * dv);
            OutT[((size_t)chunk0 * Nn + gr) * 4 + off] = o0;
            if (TN == 8) {
                float4 o1 = make_float4(acc[m][4] * dv, acc[m][5] * dv,
                                        acc[m][6] * dv, acc[m][7] * dv);
                OutT[((size_t)(4 + chunk0) * Nn + gr) * 4 + off] = o1;
            }
        }
    }
}

// ---------------------------------------------------------------------------
// FUSED (range-split): blocks [0,gemmBlocks) = GEMM1 -> hsT chunked; rest =
// atomic-free CSR fill: colu[rowptr[dst]+rank] = (ushort)src.
// ---------------------------------------------------------------------------
__global__ __launch_bounds__(256) void gemm1_fill_k(const float* __restrict__ A,
                                                    const float* __restrict__ W,
                                                    const float* __restrict__ dscale,
                                                    float4* __restrict__ OutT,
                                                    int M, int Nn,
                                                    const int* __restrict__ src,
                                                    const int* __restrict__ dst,
                                                    const int* __restrict__ rowptr,
                                                    const int* __restrict__ rank,
                                                    ushort_t* __restrict__ colu, int E,
                                                    int gemmBlocks) {
    __shared__ float As[16][36];
    __shared__ float Bs[16][128];
    int g = (int)blockIdx.x;
    if (g >= gemmBlocks) {
        int t = (g - gemmBlocks) * 256 + threadIdx.x;
        int e = t * 4;
        if (e + 4 <= E) {
            int4 s4 = *reinterpret_cast<const int4*>(src + e);
            int4 d4 = *reinterpret_cast<const int4*>(dst + e);
            int4 r4 = *reinterpret_cast<const int4*>(rank + e);
            colu[rowptr[d4.x] + r4.x] = (ushort_t)s4.x;
            colu[rowptr[d4.y] + r4.y] = (ushort_t)s4.y;
            colu[rowptr[d4.z] + r4.z] = (ushort_t)s4.z;
            colu[rowptr[d4.w] + r4.w] = (ushort_t)s4.w;
        } else {
            for (int i = e; i < E; i++)
                colu[rowptr[dst[i]] + rank[i]] = (ushort_t)src[i];
        }
        return;
    }
    gemm_body32<128, false>(A, W, dscale, OutT, M, Nn, g * 32, As, Bs);
}

__global__ __launch_bounds__(256) void gemm2_k(const float* __restrict__ A,
                                               const float* __restrict__ W,
                                               const float* __restrict__ dscale,
                                               float4* __restrict__ OutT,
                                               int M, int Nn) {
    __shared__ float As[16][36];
    __shared__ float Bs[16][64];
    gemm_body32<64, true>(A, W, dscale, OutT, M, Nn, (int)blockIdx.x * 32, As, Bs);
}

// ---------------------------------------------------------------------------
// Chunked pull body: 4 lanes per node (lane j = float4 j of the 16-float
// slice). 8-deep unrolled gather with next-block index prefetch.
// ---------------------------------------------------------------------------
__device__ __forceinline__ float4 pull_body(const int* __restrict__ rowptr,
                                            const ushort_t* __restrict__ colu,
                                            const float4* __restrict__ T,
                                            size_t cb, int v, int j) {
    int p0 = rowptr[v], p1 = rowptr[v + 1];
    float4 acc = T[(cb + v) * 4 + j];  // self row slice
    int p = p0;

    if (p + 8 <= p1) {
        int n0 = colu[p + 0], n1 = colu[p + 1], n2 = colu[p + 2], n3 = colu[p + 3];
        int n4 = colu[p + 4], n5 = colu[p + 5], n6 = colu[p + 6], n7 = colu[p + 7];
        for (;;) {
            bool nxt = (p + 16 <= p1);
            int m0, m1, m2, m3, m4, m5, m6, m7;
            if (nxt) {  // prefetch next block's indices while gathers fly
                m0 = colu[p + 8];  m1 = colu[p + 9];  m2 = colu[p + 10]; m3 = colu[p + 11];
                m4 = colu[p + 12]; m5 = colu[p + 13]; m6 = colu[p + 14]; m7 = colu[p + 15];
            }
            float4 g0 = T[(cb + n0) * 4 + j];
            float4 g1 = T[(cb + n1) * 4 + j];
            float4 g2 = T[(cb + n2) * 4 + j];
            float4 g3 = T[(cb + n3) * 4 + j];
            float4 g4 = T[(cb + n4) * 4 + j];
            float4 g5 = T[(cb + n5) * 4 + j];
            float4 g6 = T[(cb + n6) * 4 + j];
            float4 g7 = T[(cb + n7) * 4 + j];
            acc.x += ((g0.x + g1.x) + (g2.x + g3.x)) + ((g4.x + g5.x) + (g6.x + g7.x));
            acc.y += ((g0.y + g1.y) + (g2.y + g3.y)) + ((g4.y + g5.y) + (g6.y + g7.y));
            acc.z += ((g0.z + g1.z) + (g2.z + g3.z)) + ((g4.z + g5.z) + (g6.z + g7.z));
            acc.w += ((g0.w + g1.w) + (g2.w + g3.w)) + ((g4.w + g5.w) + (g6.w + g7.w));
            p += 8;
            if (!nxt) break;
            n0 = m0; n1 = m1; n2 = m2; n3 = m3;
            n4 = m4; n5 = m5; n6 = m6; n7 = m7;
        }
    }
    for (; p + 4 <= p1; p += 4) {
        int u0 = colu[p], u1 = colu[p + 1], u2 = colu[p + 2], u3 = colu[p + 3];
        float4 a = T[(cb + u0) * 4 + j];
        float4 b = T[(cb + u1) * 4 + j];
        float4 c = T[(cb + u2) * 4 + j];
        float4 d = T[(cb + u3) * 4 + j];
        acc.x += (a.x + b.x) + (c.x + d.x);
        acc.y += (a.y + b.y) + (c.y + d.y);
        acc.z += (a.z + b.z) + (c.z + d.z);
        acc.w += (a.w + b.w) + (c.w + d.w);
    }
    for (; p < p1; p++) {
        float4 a = T[(cb + colu[p]) * 4 + j];
        acc.x += a.x; acc.y += a.y; acc.z += a.z; acc.w += a.w;
    }
    return acc;
}

// pull128: blockIdx = g*8 + c -> chunk c (XCD c). Output agg1 LINEAR [N][128].
__global__ __launch_bounds__(256) void pull128c_k(const int* __restrict__ rowptr,
                                                  const ushort_t* __restrict__ colu,
                                                  const float4* __restrict__ hsT,
                                                  const float* __restrict__ dinv,
                                                  const float4* __restrict__ bias4,
                                                  float4* __restrict__ out4, int N) {
    int c = (int)(blockIdx.x & 7);
    int g = (int)(blockIdx.x >> 3);
    int v = g * 64 + (int)(threadIdx.x >> 2);
    if (v >= N) return;
    int j = threadIdx.x & 3;
    float4 acc = pull_body(rowptr, colu, hsT, (size_t)c * N, v, j);
    float dv = dinv[v];
    float4 bv = bias4[c * 4 + j];
    out4[(size_t)v * 32 + c * 4 + j] =
        make_float4(fmaf(acc.x, dv, bv.x), fmaf(acc.y, dv, bv.y),
                    fmaf(acc.z, dv, bv.z), fmaf(acc.w, dv, bv.w));
}

// pull64: blockIdx = g*4 + c (slice on XCDs c,c+4). Output agg2T CHUNKED.
__global__ __launch_bounds__(256) void pull64c_k(const int* __restrict__ rowptr,
                                                 const ushort_t* __restrict__ colu,
                                                 const float4* __restrict__ g2T,
                                                 const float* __restrict__ dinv,
                                                 const float4* __restrict__ bias4,
                                                 float4* __restrict__ outT, int N) {
    int c = (int)(blockIdx.x & 3);
    int g = (int)(blockIdx.x >> 2);
    int v = g * 64 + (int)(threadIdx.x >> 2);
    if (v >= N) return;
    int j = threadIdx.x & 3;
    size_t cb = (size_t)c * N;
    float4 acc = pull_body(rowptr, colu, g2T, cb, v, j);
    float dv = dinv[v];
    float4 bv = bias4[c * 4 + j];
    outT[(cb + v) * 4 + j] =
        make_float4(fmaf(acc.x, dv, bv.x), fmaf(acc.y, dv, bv.y),
                    fmaf(acc.z, dv, bv.z), fmaf(acc.w, dv, bv.w));
}

// ---------------------------------------------------------------------------
// logits part: edge-order, chunk c = blockIdx&3. 4-lane group per edge; both
// endpoint slices gathered (L2-pinned); part[c*E+e] coalesced.
// ---------------------------------------------------------------------------
__global__ __launch_bounds__(256) void logits_part_k(const int* __restrict__ src,
                                                     const int* __restrict__ dst,
                                                     const float4* __restrict__ aggT,
                                                     float* __restrict__ part,
                                                     int N, int E) {
    int c = (int)(blockIdx.x & 3);
    int blk = (int)(blockIdx.x >> 2);
    int g = (int)(threadIdx.x >> 2);
    int j = threadIdx.x & 3;
    size_t cb = (size_t)c * N;
    int ebase = blk * 256;

#pragma unroll
    for (int i = 0; i < 4; i++) {
        int e = ebase + i * 64 + g;
        if (e < E) {
            int s = src[e], d = dst[e];
            float4 a = aggT[(cb + s) * 4 + j];
            float4 b = aggT[(cb + d) * 4 + j];
            float t = a.x * b.x + a.y * b.y + a.z * b.z + a.w * b.w;
            t += __shfl_xor(t, 1);
            t += __shfl_xor(t, 2);
            if (j == 0) part[(size_t)c * E + e] = t;
        }
    }
}

// out[e] = sum of 4 chunk partials; coalesced float4 I/O.
__global__ __launch_bounds__(256) void logits_reduce_k(const float* __restrict__ part,
                                                       float* __restrict__ out, int E) {
    int i = blockIdx.x * blockDim.x + threadIdx.x;
    int e4 = E >> 2;
    if (i < e4) {
        const float4* p0 = reinterpret_cast<const float4*>(part);
        const float4* p1 = reinterpret_cast<const float4*>(part + (size_t)E);
        const float4* p2 = reinterpret_cast<const float4*>(part + (size_t)E * 2);
        const float4* p3 = reinterpret_cast<const float4*>(part + (size_t)E * 3);
        float4 a = p0[i], b = p1[i], c = p2[i], d = p3[i];
        float4 o = make_float4((a.x + b.x) + (c.x + d.x), (a.y + b.y) + (c.y + d.y),
                               (a.z + b.z) + (c.z + d.z), (a.w + b.w) + (c.w + d.w));
        reinterpret_cast<float4*>(out)[i] = o;
    }
    if (blockIdx.x == 0 && threadIdx.x < (E & 3)) {
        int e = e4 * 4 + threadIdx.x;
        out[e] = part[e] + part[(size_t)E + e] + part[(size_t)E * 2 + e] +
                 part[(size_t)E * 3 + e];
    }
}

extern "C" void kernel_launch(void* const* d_in, const int* in_sizes, int n_in,
                              void* d_out, int out_size, void* d_ws, size_t ws_size,
                              hipStream_t stream) {
    const float* x  = (const float*)d_in[0];
    const int* ei   = (const int*)d_in[1];   // int32 (harness converts ints)
    const float* W1 = (const float*)d_in[2];
    const float* b1 = (const float*)d_in[3];
    const float* W2 = (const float*)d_in[4];
    const float* b2 = (const float*)d_in[5];
    float* out = (float*)d_out;

    const int N = in_sizes[0] / 128;   // 50000 (< 65536 -> ushort col valid)
    const int E = in_sizes[1] / 2;     // 800000
    const int* src = ei;
    const int* dst = ei + E;

    // ---- workspace ----
    // floats: dinv[50176] | bufA[N*128] | bufB[N*128]
    //   hsT   = bufA             (chunked [8][N][16])
    //   agg1  = bufB             (linear; dead after gemm2)
    //   g2T   = bufA[0,  N*64)   (chunked [4][N][16])
    //   agg2T = bufA[N*64,N*128) (chunked [4][N][16])
    //   part  = bufB[0, 4E)      (overlays dead agg1)
    // ints: cnt[N] | incl[N] | rowptr[N+1] | bsum[256] | rank[E] | colu[E] (ushort)
    float* ws    = (float*)d_ws;
    float* dinv  = ws;
    float* bufA  = ws + 50176;
    float* bufB  = bufA + (size_t)N * 128;
    float* hsT   = bufA;
    float* agg1  = bufB;
    float* g2T   = bufA;
    float* agg2T = bufA + (size_t)N * 64;
    float* part  = bufB;

    int* ibase  = (int*)(bufB + (size_t)N * 128);
    int* cnt    = ibase;
    int* incl   = cnt + N;
    int* rowptr = incl + N;
    int* bsum   = rowptr + (N + 1);
    int* rank   = bsum + 256;
    ushort_t* colu = (ushort_t*)(rank + E);

    const int B = 256;
    const int NB = (N + 255) / 256;                  // 196
    const unsigned ng64 = (unsigned)((N + 63) / 64); // 782

    // ---- CSR count (+rank) + scan ----
    hipMemsetAsync(cnt, 0, (size_t)N * sizeof(int), stream);
    cnt_rank_k<<<(E / 4 + B - 1) / B, B, 0, stream>>>(dst, cnt, rank, E);
    scan1_k<<<NB, 256, 0, stream>>>(cnt, incl, bsum, N);
    scan23_k<<<NB, 256, 0, stream>>>(cnt, incl, bsum, rowptr, dinv, N, E, NB);

    // ---- fused: GEMM1 (hsT chunked) + atomic-free CSR fill (ushort col) ----
    {
        int gemmBlocks = (N + 31) / 32;              // 1563
        int fillBlocks = (E / 4 + B - 1) / B;        // 782
        gemm1_fill_k<<<gemmBlocks + fillBlocks, 256, 0, stream>>>(
            x, W1, dinv, (float4*)hsT, N, N, src, dst, rowptr, rank, colu, E,
            gemmBlocks);
    }

    // ---- layer 1 pull (8 chunks x 782 node-groups) -> agg1 linear ----
    pull128c_k<<<ng64 * 8, 256, 0, stream>>>(rowptr, colu, (const float4*)hsT, dinv,
                                             (const float4*)b1, (float4*)agg1, N);

    // ---- layer 2 GEMM -> g2T chunked ----
    gemm2_k<<<(N + 31) / 32, 256, 0, stream>>>(agg1, W2, dinv, (float4*)g2T, N, N);

    // ---- layer 2 pull (4 chunks x 782 node-groups) -> agg2T chunked ----
    pull64c_k<<<ng64 * 4, 256, 0, stream>>>(rowptr, colu, (const float4*)g2T, dinv,
                                            (const float4*)b2, (float4*)agg2T, N);

    // ---- logits: edge-order chunked partials + reduce ----
    {
        unsigned blk = (unsigned)((E + 255) / 256);       // 3125
        logits_part_k<<<blk * 4, 256, 0, stream>>>(src, dst, (const float4*)agg2T,
                                                   part, N, E);
        unsigned rblk = (unsigned)((E / 4 + 255) / 256);  // 782
        logits_reduce_k<<<rblk, 256, 0, stream>>>(part, out, E);
    }
}